// Round 1
// 831.255 us; speedup vs baseline: 1.0955x; 1.0955x over previous
//
#include <hip/hip_runtime.h>
#include <math.h>

#define B_  64
#define N_  1024
#define H_  64
#define IN_ 512
#define G4  256   // 4*H

// ---------------------------------------------------------------------------
// Kernel A (UNCHANGED this round): xg[m][g] = x_row(m) . W_ih[g] + b_ih + b_hh
// ---------------------------------------------------------------------------
__global__ __launch_bounds__(256) void gemm_xg_kernel(
    const float* __restrict__ x,
    const float* __restrict__ Wih,
    const float* __restrict__ bih,
    const float* __restrict__ bhh,
    float* __restrict__ xg)
{
    __shared__ float As[32][68];   // [k][m_local]
    __shared__ float Bs[32][68];   // [k][g_local]

    const int tid = threadIdx.x;
    const int g0  = blockIdx.x * 64;
    const int m0  = blockIdx.y * 64;

    const int tx = tid & 15;
    const int ty = tid >> 4;

    const int arow = tid >> 3;
    const int ak4  = tid & 7;
    const int brow = tid >> 2;
    const int bk4  = tid & 3;

    float acc[4][4] = {{0.f}};

    for (int k0 = 0; k0 < IN_; k0 += 32) {
        #pragma unroll
        for (int half = 0; half < 2; ++half) {
            const int ml = arow + half * 32;
            const int m  = m0 + ml;
            const int bb = m & 63;
            const int nn = m >> 6;
            const float4 v = *(const float4*)&x[((size_t)(bb * N_ + nn)) * IN_ + k0 + ak4 * 4];
            As[ak4 * 4 + 0][ml] = v.x;
            As[ak4 * 4 + 1][ml] = v.y;
            As[ak4 * 4 + 2][ml] = v.z;
            As[ak4 * 4 + 3][ml] = v.w;
        }
        #pragma unroll
        for (int half = 0; half < 2; ++half) {
            const int kq = bk4 + half * 4;
            const float4 v = *(const float4*)&Wih[(size_t)(g0 + brow) * IN_ + k0 + kq * 4];
            Bs[kq * 4 + 0][brow] = v.x;
            Bs[kq * 4 + 1][brow] = v.y;
            Bs[kq * 4 + 2][brow] = v.z;
            Bs[kq * 4 + 3][brow] = v.w;
        }
        __syncthreads();

        #pragma unroll
        for (int k = 0; k < 32; ++k) {
            const float4 av = *(const float4*)&As[k][ty * 4];
            const float4 bv = *(const float4*)&Bs[k][tx * 4];
            const float ar[4] = {av.x, av.y, av.z, av.w};
            const float br[4] = {bv.x, bv.y, bv.z, bv.w};
            #pragma unroll
            for (int i = 0; i < 4; ++i)
                #pragma unroll
                for (int j = 0; j < 4; ++j)
                    acc[i][j] = fmaf(ar[i], br[j], acc[i][j]);
        }
        __syncthreads();
    }

    float bias[4];
    #pragma unroll
    for (int j = 0; j < 4; ++j)
        bias[j] = bih[g0 + tx * 4 + j] + bhh[g0 + tx * 4 + j];

    #pragma unroll
    for (int i = 0; i < 4; ++i) {
        const int m = m0 + ty * 4 + i;
        float4 o;
        o.x = acc[i][0] + bias[0];
        o.y = acc[i][1] + bias[1];
        o.z = acc[i][2] + bias[2];
        o.w = acc[i][3] + bias[3];
        *(float4*)&xg[(size_t)m * G4 + g0 + tx * 4] = o;
    }
}

// ---------------------------------------------------------------------------
// Kernel B: recurrent scan, restructured.
//   512 threads/block (8 waves), one block per batch row.
//   Thread pair (2g, 2g+1) splits gate g's 64-long dot product:
//     - 32 weights/thread -> 8 float4 = 32 VGPRs, genuinely register-resident
//       (the old 64-float/thread version reported VGPR_Count=48 -> weights
//        were being re-loaded from memory inside EVERY step).
//     - 4 independent accumulators -> dependent-FMA chain 8 deep, not 64.
//     - halves combined with one __shfl_xor (same wave, lanes differ in bit0).
//   ONE barrier per step:
//     - every wave redundantly computes the full 64-wide cell update
//       (identical inputs -> bitwise-identical LDS writes, benign races),
//       so no wave waits on a wave-0-only serial section and no 2nd barrier.
//     - gate LDS is double-buffered: a fast wave's step-(n+1) gate writes
//       (pre-barrier) land in the other buffer than a slow wave's step-n
//       gate reads (post-barrier). h_sh needs no double buffer: all
//       conflicting h writes carry identical values.
//   Activations use hardware v_rcp_f32 (error ~1e-7; tolerance is ~4e-3).
// ---------------------------------------------------------------------------
__device__ __forceinline__ float fast_rcp(float x) {
    return __builtin_amdgcn_rcpf(x);
}

__global__ __launch_bounds__(512) void lstm_scan_kernel(
    const float* __restrict__ xg,    // [N][B][256]
    const float* __restrict__ Whh,   // [256][64]
    float* __restrict__ out)         // [B][N][64]
{
    const int t    = threadIdx.x;      // 0..511
    const int bb   = blockIdx.x;       // batch row
    const int g    = t >> 1;           // gate 0..255
    const int half = t & 1;            // which half of the dot
    const int l    = t & 63;           // h index for the redundant update

    __shared__ float h_sh[64];
    __shared__ float gate_sh[2][256];

    // Half of W_hh row g -> 8 float4 = 32 VGPRs (fits: stays in registers).
    float4 w[8];
    {
        const float* wrow = &Whh[(size_t)g * H_ + half * 32];
        #pragma unroll
        for (int q = 0; q < 8; ++q)
            w[q] = *(const float4*)&wrow[q * 4];
    }

    float c = 0.f;                     // cell state (replicated per wave)
    if (t < 64) h_sh[t] = 0.f;
    __syncthreads();

    // wave-uniform activation selector: gates 128..191 (tanh) = waves 4,5
    const bool is_tanh_gate = (t >= 256) && (t < 384);

    float xg_cur = xg[(size_t)bb * G4 + g];   // n = 0

    for (int n = 0; n < N_; ++n) {
        const int wb = n & 1;          // gate buffer written/read this step

        // prefetch next step's xg (hides L2/L3 latency behind the dot)
        const int n1 = (n + 1 < N_) ? (n + 1) : (N_ - 1);
        const float xg_next = xg[((size_t)n1 * B_ + bb) * G4 + g];

        // --- half-dot: W_hh[g][half*32 .. +32) . h, 4-way ILP ---
        const float* hbase = &h_sh[half * 32];
        float a0 = 0.f, a1 = 0.f, a2 = 0.f, a3 = 0.f;
        #pragma unroll
        for (int q = 0; q < 8; ++q) {
            const float4 hv = *(const float4*)&hbase[q * 4];
            a0 = fmaf(w[q].x, hv.x, a0);
            a1 = fmaf(w[q].y, hv.y, a1);
            a2 = fmaf(w[q].z, hv.z, a2);
            a3 = fmaf(w[q].w, hv.w, a3);
        }
        float acc = (a0 + a1) + (a2 + a3);
        acc += __shfl_xor(acc, 1);     // combine halves (same wave)
        acc += xg_cur;

        // --- activation (wave-uniform branch) ---
        float v;
        if (is_tanh_gate) {
            v = 1.f - 2.f * fast_rcp(1.f + __expf(2.f * acc));   // tanh
        } else {
            v = fast_rcp(1.f + __expf(-acc));                    // sigmoid
        }
        gate_sh[wb][g] = v;            // both halves write same value (benign)

        __syncthreads();               // the ONLY barrier per step

        // --- redundant cell update: every wave computes all 64 lanes ---
        const float gi = gate_sh[wb][l];
        const float gf = gate_sh[wb][64 + l];
        const float gg = gate_sh[wb][128 + l];
        const float go = gate_sh[wb][192 + l];
        c = fmaf(gf, c, gi * gg);
        const float th = 1.f - 2.f * fast_rcp(1.f + __expf(2.f * c)); // tanh(c)
        const float h  = go * th;
        h_sh[l] = h;                   // identical values across waves (benign)
        if (t < 64)                    // wave 0 only: global store
            out[((size_t)bb * N_ + n) * H_ + l] = h;

        xg_cur = xg_next;
    }
}

extern "C" void kernel_launch(void* const* d_in, const int* in_sizes, int n_in,
                              void* d_out, int out_size, void* d_ws, size_t ws_size,
                              hipStream_t stream)
{
    const float* x   = (const float*)d_in[0];
    const float* Wih = (const float*)d_in[1];
    const float* Whh = (const float*)d_in[2];
    const float* bih = (const float*)d_in[3];
    const float* bhh = (const float*)d_in[4];
    float* out = (float*)d_out;
    float* xg  = (float*)d_ws;   // 65536 * 256 * 4 B = 64 MiB scratch

    dim3 ggrid(4, 1024);   // (g-tiles, m-tiles)
    gemm_xg_kernel<<<ggrid, 256, 0, stream>>>(x, Wih, bih, bhh, xg);
    lstm_scan_kernel<<<64, 512, 0, stream>>>(xg, Whh, out);
}